// Round 1
// 547.890 us; speedup vs baseline: 2.0628x; 2.0628x over previous
//
#include <hip/hip_runtime.h>

constexpr int NB   = 64;                 // graphs per batch
constexpr int NPG  = 1024;               // nodes per graph
constexpr int EPG  = 16384;              // edges per graph
constexpr int NTOT = NB * NPG;           // 65536 nodes
constexpr int ETOT = NB * EPG;           // 1048576 edges
constexpr int FIN  = 64;
constexpr int FHID = 128;
constexpr int FOUT = 32;

// ------------------------------------------------- degrees via LDS histogram
__global__ __launch_bounds__(1024) void k_deg(
    const int* __restrict__ src, const int* __restrict__ dst,
    int* __restrict__ dego, int* __restrict__ degi) {
  __shared__ int so[NPG], si[NPG];
  const int g = blockIdx.x, q = blockIdx.y;
  for (int i = threadIdx.x; i < NPG; i += 1024) { so[i] = 0; si[i] = 0; }
  __syncthreads();
  const int eb = g * EPG + q * (EPG / 4);
  const int gb = g * NPG;
  for (int e = threadIdx.x; e < EPG / 4; e += 1024) {
    atomicAdd(&so[src[eb + e] - gb], 1);
    atomicAdd(&si[dst[eb + e] - gb], 1);
  }
  __syncthreads();
  for (int i = threadIdx.x; i < NPG; i += 1024) {
    if (so[i]) atomicAdd(&dego[gb + i], so[i]);
    if (si[i]) atomicAdd(&degi[gb + i], si[i]);
  }
}

__global__ void k_scales(const int* __restrict__ dego, const int* __restrict__ degi,
                         float* __restrict__ rso, float* __restrict__ rsi) {
  int i = blockIdx.x * blockDim.x + threadIdx.x;
  if (i < NTOT) {
    int a = dego[i] > 1 ? dego[i] : 1;
    int b = degi[i] > 1 ? degi[i] : 1;
    rso[i] = rsqrtf((float)a);
    rsi[i] = rsqrtf((float)b);
  }
}

// ------------------------------------------------- CSR build: per-graph scan
// ptr[n] = absolute start of node n's in-edge bucket; cursor = running copy.
__global__ __launch_bounds__(1024) void k_scan(
    const int* __restrict__ degi, int* __restrict__ ptr, int* __restrict__ cursor) {
  __shared__ int s[NPG];
  const int g = blockIdx.x, t = threadIdx.x;
  const int d = degi[g * NPG + t];
  s[t] = d;
  __syncthreads();
  for (int off = 1; off < NPG; off <<= 1) {
    int v = (t >= off) ? s[t - off] : 0;
    __syncthreads();
    s[t] += v;
    __syncthreads();
  }
  const int p = g * EPG + (s[t] - d);       // exclusive scan, absolute offset
  ptr[g * NPG + t] = p;
  cursor[g * NPG + t] = p;
  if (g == 0 && t == 0) ptr[NTOT] = ETOT;
}

// ------------------------------------------------- CSR build: fill buckets
__global__ void k_fill(const int* __restrict__ src, const int* __restrict__ dst,
                       int* __restrict__ cursor, int* __restrict__ csr) {
  int e = blockIdx.x * blockDim.x + threadIdx.x;
  if (e < ETOT) {
    int d = dst[e];
    int pos = atomicAdd(&cursor[d], 1);
    csr[pos] = src[e];
  }
}

// ------------------------------------------------- prefold: x1 = features * rs_out
__global__ void k_prefold(const float* __restrict__ features,
                          const int* __restrict__ dego, float* __restrict__ x1) {
  int t = blockIdx.x * blockDim.x + threadIdx.x;   // NTOT*16 threads
  int node = t >> 4, q = t & 15;
  int dg = dego[node];
  float sc = rsqrtf((float)(dg > 1 ? dg : 1));
  float4 v = *(const float4*)&features[(size_t)node * FIN + q * 4];
  v.x *= sc; v.y *= sc; v.z *= sc; v.w *= sc;
  *(float4*)&x1[(size_t)node * FIN + q * 4] = v;
}

// ------------------------------------------------- CSR aggregation
// One wave per destination node; lane = feature dim (64 = FIN).
// Up to 64 edge indices loaded in ONE coalesced wave-load, broadcast via
// readlane; each edge is one fully-coalesced 256B row gather accumulated in
// a single register. No LDS, no atomics. Output pre-scaled by rs_in.
__global__ __launch_bounds__(256) void k_agg_csr(
    const int* __restrict__ ptr, const int* __restrict__ csr,
    const float* __restrict__ x, const float* __restrict__ rsi,
    float* __restrict__ out) {
  const int nblk = gridDim.x;                       // 16384, divisible by 8
  const int bid  = blockIdx.x;
  const int swz  = (bid & 7) * (nblk >> 3) + (bid >> 3);   // XCD-contiguous
  const int node = swz * 4 + (threadIdx.x >> 6);
  const int lane = threadIdx.x & 63;

  const int start = ptr[node];
  const int end   = ptr[node + 1];
  const int deg   = end - start;

  float acc = 0.0f;
  const float* xb = x + lane;
  if (deg > 0) {
    const int jm = deg < 64 ? deg : 64;
    const int idxv = csr[start + (lane < jm ? lane : 0)];   // 1 coalesced load
    for (int j = 0; j < jm; j += 8) {
      int   sj[8];
      float vj[8];
#pragma unroll
      for (int u = 0; u < 8; ++u) {
        int l = j + u;
        sj[u] = __builtin_amdgcn_readlane(idxv, l < jm ? l : 0);
      }
#pragma unroll
      for (int u = 0; u < 8; ++u) vj[u] = xb[(size_t)sj[u] * FIN];
#pragma unroll
      for (int u = 0; u < 8; ++u) acc += (j + u < jm) ? vj[u] : 0.0f;
    }
    // pathological multi-edge tail (deg > 64): uniform serial loop, ~never taken
    for (int e = start + 64; e < end; ++e) acc += xb[(size_t)csr[e] * FIN];
  }
  out[(size_t)node * FIN + lane] = acc * rsi[node];
}

// ------------------------------------------------- GEMM1: h = relu(m1@W1 + b1) * rs_out
__global__ __launch_bounds__(256) void k_gemm1(
    const float* __restrict__ m1, const float* __restrict__ rso,
    const float* __restrict__ W1, const float* __restrict__ b1,
    float* __restrict__ h) {
  __shared__ float sA[FIN][64];          // [k][node], 16 KB
  __shared__ float sW[FIN * FHID];       // [k][j],    32 KB
  __shared__ float sB[FHID];
  const int t = threadIdx.x;
  const int node0 = blockIdx.x * 64;
  for (int f = t; f < FIN * FHID / 4; f += 256)
    ((float4*)sW)[f] = ((const float4*)W1)[f];
  if (t < FHID) sB[t] = b1[t];
  for (int f = t; f < 64 * (FIN / 4); f += 256) {
    int node = f & 63, kq = f >> 6;
    size_t idx = (size_t)(node0 + node) * FIN + kq * 4;
    float4 va = *(const float4*)&m1[idx];
    sA[kq * 4 + 0][node] = va.x;
    sA[kq * 4 + 1][node] = va.y;
    sA[kq * 4 + 2][node] = va.z;
    sA[kq * 4 + 3][node] = va.w;
  }
  __syncthreads();
  const int tx = t & 15, ty = t >> 4;    // j0 = tx*8, n0 = ty*4
  float acc[4][8];
#pragma unroll
  for (int r = 0; r < 4; ++r)
#pragma unroll
    for (int c = 0; c < 8; ++c) acc[r][c] = 0.0f;
#pragma unroll 4
  for (int k = 0; k < FIN; ++k) {
    float4 a  = *(float4*)&sA[k][ty * 4];
    float4 w0 = *(float4*)&sW[k * FHID + tx * 8];
    float4 w1 = *(float4*)&sW[k * FHID + tx * 8 + 4];
    float av[4] = {a.x, a.y, a.z, a.w};
    float wv[8] = {w0.x, w0.y, w0.z, w0.w, w1.x, w1.y, w1.z, w1.w};
#pragma unroll
    for (int r = 0; r < 4; ++r)
#pragma unroll
      for (int c = 0; c < 8; ++c) acc[r][c] = fmaf(av[r], wv[c], acc[r][c]);
  }
#pragma unroll
  for (int r = 0; r < 4; ++r) {
    int node = node0 + ty * 4 + r;
    float sc = rso[node];
    float4 o0, o1;
    o0.x = fmaxf(acc[r][0] + sB[tx * 8 + 0], 0.f) * sc;
    o0.y = fmaxf(acc[r][1] + sB[tx * 8 + 1], 0.f) * sc;
    o0.z = fmaxf(acc[r][2] + sB[tx * 8 + 2], 0.f) * sc;
    o0.w = fmaxf(acc[r][3] + sB[tx * 8 + 3], 0.f) * sc;
    o1.x = fmaxf(acc[r][4] + sB[tx * 8 + 4], 0.f) * sc;
    o1.y = fmaxf(acc[r][5] + sB[tx * 8 + 5], 0.f) * sc;
    o1.z = fmaxf(acc[r][6] + sB[tx * 8 + 6], 0.f) * sc;
    o1.w = fmaxf(acc[r][7] + sB[tx * 8 + 7], 0.f) * sc;
    *(float4*)&h[(size_t)node * FHID + tx * 8]     = o0;
    *(float4*)&h[(size_t)node * FHID + tx * 8 + 4] = o1;
  }
}

// ------------------------------------------------- GEMM2: p = h @ [W2 | W3]
__global__ __launch_bounds__(256) void k_gemm2(
    const float* __restrict__ h, const float* __restrict__ W2,
    const float* __restrict__ W3, float* __restrict__ p) {
  __shared__ float sA[FHID][64];         // [k][node], 32 KB
  __shared__ float sW[FHID * 64];        // [k][j], j<32 -> W2, else W3, 32 KB
  const int t = threadIdx.x;
  const int node0 = blockIdx.x * 64;
  for (int f = t; f < FHID * FOUT / 4; f += 256) {
    int k = f >> 3, jq = f & 7;
    *(float4*)&sW[k * 64 + jq * 4]      = *(const float4*)&W2[k * FOUT + jq * 4];
  }
  for (int f = t; f < FHID * FOUT / 4; f += 256) {
    int k = f >> 3, jq = f & 7;
    *(float4*)&sW[k * 64 + 32 + jq * 4] = *(const float4*)&W3[k * FOUT + jq * 4];
  }
  for (int f = t; f < 64 * (FHID / 4); f += 256) {
    int node = f & 63, kq = f >> 6;
    float4 v = *(const float4*)&h[(size_t)(node0 + node) * FHID + kq * 4];
    sA[kq * 4 + 0][node] = v.x;
    sA[kq * 4 + 1][node] = v.y;
    sA[kq * 4 + 2][node] = v.z;
    sA[kq * 4 + 3][node] = v.w;
  }
  __syncthreads();
  const int tx = t & 15, ty = t >> 4;    // j0 = tx*4, n0 = ty*4
  float acc[4][4];
#pragma unroll
  for (int r = 0; r < 4; ++r)
#pragma unroll
    for (int c = 0; c < 4; ++c) acc[r][c] = 0.0f;
#pragma unroll 4
  for (int k = 0; k < FHID; ++k) {
    float4 a = *(float4*)&sA[k][ty * 4];
    float4 w = *(float4*)&sW[k * 64 + tx * 4];
    float av[4] = {a.x, a.y, a.z, a.w};
    float wv[4] = {w.x, w.y, w.z, w.w};
#pragma unroll
    for (int r = 0; r < 4; ++r)
#pragma unroll
      for (int c = 0; c < 4; ++c) acc[r][c] = fmaf(av[r], wv[c], acc[r][c]);
  }
#pragma unroll
  for (int r = 0; r < 4; ++r) {
    float4 o = {acc[r][0], acc[r][1], acc[r][2], acc[r][3]};
    *(float4*)&p[(size_t)(node0 + ty * 4 + r) * 64 + tx * 4] = o;
  }
}

// ------------------------------------------------- epilogue: mean / log_std
// m2 is already rs_in-scaled by k_agg_csr; just add biases and split.
__global__ void k_epi(const float* __restrict__ m2,
                      const float* __restrict__ b2, const float* __restrict__ b3,
                      float* __restrict__ mean_, float* __restrict__ logstd_) {
  int t = blockIdx.x * blockDim.x + threadIdx.x;   // NTOT*8 threads
  int node = t >> 3, q = t & 7;
  size_t im = (size_t)node * 64 + q * 4;
  size_t il = im + 32;
  float4 ma = *(const float4*)&m2[im];
  float4 la = *(const float4*)&m2[il];
  float4 bb2 = *(const float4*)&b2[q * 4];
  float4 bb3 = *(const float4*)&b3[q * 4];
  float4 me = {ma.x + bb2.x, ma.y + bb2.y, ma.z + bb2.z, ma.w + bb2.w};
  float4 ls = {la.x + bb3.x, la.y + bb3.y, la.z + bb3.z, la.w + bb3.w};
  *(float4*)&mean_[(size_t)node * FOUT + q * 4]   = me;
  *(float4*)&logstd_[(size_t)node * FOUT + q * 4] = ls;
}

// ------------------------------------------------- adj = sigmoid(z z^T) per graph
__global__ __launch_bounds__(256) void k_adj(
    const float* __restrict__ mean_, const float* __restrict__ logstd_,
    const float* __restrict__ noise, float* __restrict__ adj) {
  __shared__ float sR[FOUT][128];
  __shared__ float sC[FOUT][128];
  const int g  = blockIdx.z;
  const int c0 = blockIdx.x * 128;
  const int r0 = blockIdx.y * 128;
  const int t  = threadIdx.x;
  const size_t gb = (size_t)g * NPG;
  for (int f = t; f < 2048; f += 256) {
    int half = f >> 10;
    int ff   = f & 1023;
    int node = ff & 127, kq = ff >> 7;
    int base = half ? c0 : r0;
    size_t idx = (gb + base + node) * FOUT + kq * 4;
    float4 m  = *(const float4*)&mean_[idx];
    float4 l  = *(const float4*)&logstd_[idx];
    float4 nz = *(const float4*)&noise[idx];
    float* s = half ? &sC[0][0] : &sR[0][0];
    s[(kq * 4 + 0) * 128 + node] = m.x + nz.x * __expf(l.x);
    s[(kq * 4 + 1) * 128 + node] = m.y + nz.y * __expf(l.y);
    s[(kq * 4 + 2) * 128 + node] = m.z + nz.z * __expf(l.z);
    s[(kq * 4 + 3) * 128 + node] = m.w + nz.w * __expf(l.w);
  }
  __syncthreads();
  const int tx = t & 15, ty = t >> 4;
  float acc[8][8];
#pragma unroll
  for (int r = 0; r < 8; ++r)
#pragma unroll
    for (int c = 0; c < 8; ++c) acc[r][c] = 0.0f;
#pragma unroll 2
  for (int k = 0; k < FOUT; ++k) {
    float ar[8], ac[8];
    *(float4*)&ar[0] = *(float4*)&sR[k][ty * 8];
    *(float4*)&ar[4] = *(float4*)&sR[k][ty * 8 + 4];
    *(float4*)&ac[0] = *(float4*)&sC[k][tx * 8];
    *(float4*)&ac[4] = *(float4*)&sC[k][tx * 8 + 4];
#pragma unroll
    for (int r = 0; r < 8; ++r)
#pragma unroll
      for (int c = 0; c < 8; ++c) acc[r][c] = fmaf(ar[r], ac[c], acc[r][c]);
  }
#pragma unroll
  for (int r = 0; r < 8; ++r) {
    size_t o = (gb + r0 + ty * 8 + r) * (size_t)NPG + c0 + tx * 8;
    float4 s0, s1;
    s0.x = 1.0f / (1.0f + __expf(-acc[r][0]));
    s0.y = 1.0f / (1.0f + __expf(-acc[r][1]));
    s0.z = 1.0f / (1.0f + __expf(-acc[r][2]));
    s0.w = 1.0f / (1.0f + __expf(-acc[r][3]));
    s1.x = 1.0f / (1.0f + __expf(-acc[r][4]));
    s1.y = 1.0f / (1.0f + __expf(-acc[r][5]));
    s1.z = 1.0f / (1.0f + __expf(-acc[r][6]));
    s1.w = 1.0f / (1.0f + __expf(-acc[r][7]));
    *(float4*)&adj[o]     = s0;
    *(float4*)&adj[o + 4] = s1;
  }
}

extern "C" void kernel_launch(void* const* d_in, const int* in_sizes, int n_in,
                              void* d_out, int out_size, void* d_ws, size_t ws_size,
                              hipStream_t stream) {
  const float* features = (const float*)d_in[0];
  const int*   src      = (const int*)d_in[1];
  const int*   dst      = (const int*)d_in[2];
  const float* noise    = (const float*)d_in[3];
  const float* W1       = (const float*)d_in[4];
  const float* b1       = (const float*)d_in[5];
  const float* W2       = (const float*)d_in[6];
  const float* b2       = (const float*)d_in[7];
  const float* W3       = (const float*)d_in[8];
  const float* b3       = (const float*)d_in[9];

  float* adj     = (float*)d_out;                              // 64*1024*1024
  float* mean_   = adj + (size_t)NB * NPG * NPG;               // N*32
  float* logstd_ = mean_ + (size_t)NTOT * FOUT;                // N*32

  // Scratch inside the adj region (written only by the final kernel, which
  // reads nothing from it). Float4-accessed buffers first for 16B alignment.
  float* x1   = adj;                              // N*64  (features * rs_out)
  float* m1   = x1 + (size_t)NTOT * FIN;          // N*64  (rs_in-scaled agg)
  float* h    = m1 + (size_t)NTOT * FIN;          // N*128
  float* p    = h + (size_t)NTOT * FHID;          // N*64
  float* m2   = p + (size_t)NTOT * FIN;           // N*64
  int*   dego = (int*)(m2 + (size_t)NTOT * FIN);  // N ints
  int*   degi = dego + NTOT;                      // N ints
  float* rso  = (float*)(degi + NTOT);            // N
  float* rsi  = rso + NTOT;                       // N
  int*   ptr  = (int*)(rsi + NTOT);               // N+1
  int*   cur  = ptr + (NTOT + 1);                 // N
  int*   csr  = cur + NTOT;                       // ETOT (4 MB)

  hipMemsetAsync(dego, 0, (size_t)2 * NTOT * sizeof(int), stream);
  k_deg<<<dim3(NB, 4), 1024, 0, stream>>>(src, dst, dego, degi);
  k_scales<<<NTOT / 256, 256, 0, stream>>>(dego, degi, rso, rsi);
  // CSR (built once, used by both layers)
  k_scan<<<NB, 1024, 0, stream>>>(degi, ptr, cur);
  k_fill<<<ETOT / 256, 256, 0, stream>>>(src, dst, cur, csr);
  k_prefold<<<NTOT * 16 / 256, 256, 0, stream>>>(features, dego, x1);
  // layer 1 aggregate: m1 = rs_in * Agg(x1)
  k_agg_csr<<<NTOT / 4, 256, 0, stream>>>(ptr, csr, x1, rsi, m1);
  // h = relu(m1 @ W1 + b1) * rs_out
  k_gemm1<<<NTOT / 64, 256, 0, stream>>>(m1, rso, W1, b1, h);
  // p = h @ [W2 | W3]  (project BEFORE aggregating: halves scatter traffic)
  k_gemm2<<<NTOT / 64, 256, 0, stream>>>(h, W2, W3, p);
  // layer 2 aggregate: m2 = rs_in * Agg(p)
  k_agg_csr<<<NTOT / 4, 256, 0, stream>>>(ptr, csr, p, rsi, m2);
  k_epi<<<NTOT * 8 / 256, 256, 0, stream>>>(m2, b2, b3, mean_, logstd_);
  k_adj<<<dim3(NPG / 128, NPG / 128, NB), 256, 0, stream>>>(mean_, logstd_, noise, adj);
}

// Round 3
// 528.700 us; speedup vs baseline: 2.1377x; 1.0363x over previous
//
#include <hip/hip_runtime.h>

constexpr int NB   = 64;                 // graphs per batch
constexpr int NPG  = 1024;               // nodes per graph
constexpr int EPG  = 16384;              // edges per graph
constexpr int NTOT = NB * NPG;           // 65536 nodes
constexpr int ETOT = NB * EPG;           // 1048576 edges
constexpr int FIN  = 64;
constexpr int FHID = 128;
constexpr int FOUT = 32;

// ------------------------------------------------- degrees via LDS histogram
__global__ __launch_bounds__(1024) void k_deg(
    const int* __restrict__ src, const int* __restrict__ dst,
    int* __restrict__ dego, int* __restrict__ degi) {
  __shared__ int so[NPG], si[NPG];
  const int g = blockIdx.x, q = blockIdx.y;
  for (int i = threadIdx.x; i < NPG; i += 1024) { so[i] = 0; si[i] = 0; }
  __syncthreads();
  const int eb = g * EPG + q * (EPG / 4);
  const int gb = g * NPG;
  for (int e = threadIdx.x; e < EPG / 4; e += 1024) {
    atomicAdd(&so[src[eb + e] - gb], 1);
    atomicAdd(&si[dst[eb + e] - gb], 1);
  }
  __syncthreads();
  for (int i = threadIdx.x; i < NPG; i += 1024) {
    if (so[i]) atomicAdd(&dego[gb + i], so[i]);
    if (si[i]) atomicAdd(&degi[gb + i], si[i]);
  }
}

__global__ void k_scales(const int* __restrict__ dego, const int* __restrict__ degi,
                         float* __restrict__ rso, float* __restrict__ rsi) {
  int i = blockIdx.x * blockDim.x + threadIdx.x;
  if (i < NTOT) {
    int a = dego[i] > 1 ? dego[i] : 1;
    int b = degi[i] > 1 ? degi[i] : 1;
    rso[i] = rsqrtf((float)a);
    rsi[i] = rsqrtf((float)b);
  }
}

// ------------------------------------------------- CSR build: per-graph scan
__global__ __launch_bounds__(1024) void k_scan(
    const int* __restrict__ degi, int* __restrict__ ptr, int* __restrict__ cursor) {
  __shared__ int s[NPG];
  const int g = blockIdx.x, t = threadIdx.x;
  const int d = degi[g * NPG + t];
  s[t] = d;
  __syncthreads();
  for (int off = 1; off < NPG; off <<= 1) {
    int v = (t >= off) ? s[t - off] : 0;
    __syncthreads();
    s[t] += v;
    __syncthreads();
  }
  const int p = g * EPG + (s[t] - d);       // exclusive scan, absolute offset
  ptr[g * NPG + t] = p;
  cursor[g * NPG + t] = p;
  if (g == 0 && t == 0) ptr[NTOT] = ETOT;
}

// ------------------------------------------------- CSR build: fill buckets
__global__ void k_fill(const int* __restrict__ src, const int* __restrict__ dst,
                       int* __restrict__ cursor, int* __restrict__ csr) {
  int e = blockIdx.x * blockDim.x + threadIdx.x;
  if (e < ETOT) {
    int d = dst[e];
    int pos = atomicAdd(&cursor[d], 1);
    csr[pos] = src[e];
  }
}

// ------------------------------------------------- prefold: x1 = features * rs_out
__global__ void k_prefold(const float* __restrict__ features,
                          const int* __restrict__ dego, float* __restrict__ x1) {
  int t = blockIdx.x * blockDim.x + threadIdx.x;   // NTOT*16 threads
  int node = t >> 4, q = t & 15;
  int dg = dego[node];
  float sc = rsqrtf((float)(dg > 1 ? dg : 1));
  float4 v = *(const float4*)&features[(size_t)node * FIN + q * 4];
  v.x *= sc; v.y *= sc; v.z *= sc; v.w *= sc;
  *(float4*)&x1[(size_t)node * FIN + q * 4] = v;
}

// ------------------------------------------------- CSR aggregation (layer 1)
// One wave per destination node; lane = feature dim (64 = FIN).
__global__ __launch_bounds__(256) void k_agg_csr(
    const int* __restrict__ ptr, const int* __restrict__ csr,
    const float* __restrict__ x, const float* __restrict__ rsi,
    float* __restrict__ out) {
  const int nblk = gridDim.x;                       // 16384, divisible by 8
  const int bid  = blockIdx.x;
  const int swz  = (bid & 7) * (nblk >> 3) + (bid >> 3);   // XCD-contiguous
  const int node = swz * 4 + (threadIdx.x >> 6);
  const int lane = threadIdx.x & 63;

  const int start = ptr[node];
  const int end   = ptr[node + 1];
  const int deg   = end - start;

  float acc = 0.0f;
  const float* xb = x + lane;
  if (deg > 0) {
    const int jm = deg < 64 ? deg : 64;
    const int idxv = csr[start + (lane < jm ? lane : 0)];   // 1 coalesced load
    for (int j = 0; j < jm; j += 8) {
      int   sj[8];
      float vj[8];
#pragma unroll
      for (int u = 0; u < 8; ++u) {
        int l = j + u;
        sj[u] = __builtin_amdgcn_readlane(idxv, l < jm ? l : 0);
      }
#pragma unroll
      for (int u = 0; u < 8; ++u) vj[u] = xb[(size_t)sj[u] * FIN];
#pragma unroll
      for (int u = 0; u < 8; ++u) acc += (j + u < jm) ? vj[u] : 0.0f;
    }
    for (int e = start + 64; e < end; ++e) acc += xb[(size_t)csr[e] * FIN];
  }
  out[(size_t)node * FIN + lane] = acc * rsi[node];
}

// ------------------------------------------------- CSR aggregation (layer 2)
// Same gather; epilogue fuses rs_in scale + bias and splits mean/logstd.
__global__ __launch_bounds__(256) void k_agg2(
    const int* __restrict__ ptr, const int* __restrict__ csr,
    const float* __restrict__ x, const float* __restrict__ rsi,
    const float* __restrict__ b2, const float* __restrict__ b3,
    float* __restrict__ mean_, float* __restrict__ logstd_) {
  const int nblk = gridDim.x;
  const int bid  = blockIdx.x;
  const int swz  = (bid & 7) * (nblk >> 3) + (bid >> 3);
  const int node = swz * 4 + (threadIdx.x >> 6);
  const int lane = threadIdx.x & 63;

  const int start = ptr[node];
  const int end   = ptr[node + 1];
  const int deg   = end - start;

  float acc = 0.0f;
  const float* xb = x + lane;
  if (deg > 0) {
    const int jm = deg < 64 ? deg : 64;
    const int idxv = csr[start + (lane < jm ? lane : 0)];
    for (int j = 0; j < jm; j += 8) {
      int   sj[8];
      float vj[8];
#pragma unroll
      for (int u = 0; u < 8; ++u) {
        int l = j + u;
        sj[u] = __builtin_amdgcn_readlane(idxv, l < jm ? l : 0);
      }
#pragma unroll
      for (int u = 0; u < 8; ++u) vj[u] = xb[(size_t)sj[u] * FIN];
#pragma unroll
      for (int u = 0; u < 8; ++u) acc += (j + u < jm) ? vj[u] : 0.0f;
    }
    for (int e = start + 64; e < end; ++e) acc += xb[(size_t)csr[e] * FIN];
  }
  const float bias = (lane < FOUT) ? b2[lane] : b3[lane - FOUT];
  const float v = acc * rsi[node] + bias;
  if (lane < FOUT) mean_[(size_t)node * FOUT + lane] = v;
  else             logstd_[(size_t)node * FOUT + (lane - FOUT)] = v;
}

// ------------------------------------------------- GEMM1: h = relu(m1@W1 + b1) * rs_out
__global__ __launch_bounds__(256) void k_gemm1(
    const float* __restrict__ m1, const float* __restrict__ rso,
    const float* __restrict__ W1, const float* __restrict__ b1,
    float* __restrict__ h) {
  __shared__ float sA[FIN][64];          // [k][node], 16 KB
  __shared__ float sW[FIN * FHID];       // [k][j],    32 KB
  __shared__ float sB[FHID];
  const int t = threadIdx.x;
  const int node0 = blockIdx.x * 64;
  for (int f = t; f < FIN * FHID / 4; f += 256)
    ((float4*)sW)[f] = ((const float4*)W1)[f];
  if (t < FHID) sB[t] = b1[t];
  for (int f = t; f < 64 * (FIN / 4); f += 256) {
    int node = f & 63, kq = f >> 6;
    size_t idx = (size_t)(node0 + node) * FIN + kq * 4;
    float4 va = *(const float4*)&m1[idx];
    sA[kq * 4 + 0][node] = va.x;
    sA[kq * 4 + 1][node] = va.y;
    sA[kq * 4 + 2][node] = va.z;
    sA[kq * 4 + 3][node] = va.w;
  }
  __syncthreads();
  const int tx = t & 15, ty = t >> 4;    // j0 = tx*8, n0 = ty*4
  float acc[4][8];
#pragma unroll
  for (int r = 0; r < 4; ++r)
#pragma unroll
    for (int c = 0; c < 8; ++c) acc[r][c] = 0.0f;
#pragma unroll 4
  for (int k = 0; k < FIN; ++k) {
    float4 a  = *(float4*)&sA[k][ty * 4];
    float4 w0 = *(float4*)&sW[k * FHID + tx * 8];
    float4 w1 = *(float4*)&sW[k * FHID + tx * 8 + 4];
    float av[4] = {a.x, a.y, a.z, a.w};
    float wv[8] = {w0.x, w0.y, w0.z, w0.w, w1.x, w1.y, w1.z, w1.w};
#pragma unroll
    for (int r = 0; r < 4; ++r)
#pragma unroll
      for (int c = 0; c < 8; ++c) acc[r][c] = fmaf(av[r], wv[c], acc[r][c]);
  }
#pragma unroll
  for (int r = 0; r < 4; ++r) {
    int node = node0 + ty * 4 + r;
    float sc = rso[node];
    float4 o0, o1;
    o0.x = fmaxf(acc[r][0] + sB[tx * 8 + 0], 0.f) * sc;
    o0.y = fmaxf(acc[r][1] + sB[tx * 8 + 1], 0.f) * sc;
    o0.z = fmaxf(acc[r][2] + sB[tx * 8 + 2], 0.f) * sc;
    o0.w = fmaxf(acc[r][3] + sB[tx * 8 + 3], 0.f) * sc;
    o1.x = fmaxf(acc[r][4] + sB[tx * 8 + 4], 0.f) * sc;
    o1.y = fmaxf(acc[r][5] + sB[tx * 8 + 5], 0.f) * sc;
    o1.z = fmaxf(acc[r][6] + sB[tx * 8 + 6], 0.f) * sc;
    o1.w = fmaxf(acc[r][7] + sB[tx * 8 + 7], 0.f) * sc;
    *(float4*)&h[(size_t)node * FHID + tx * 8]     = o0;
    *(float4*)&h[(size_t)node * FHID + tx * 8 + 4] = o1;
  }
}

// ------------------------------------------------- GEMM2: p = h @ [W2 | W3]
__global__ __launch_bounds__(256) void k_gemm2(
    const float* __restrict__ h, const float* __restrict__ W2,
    const float* __restrict__ W3, float* __restrict__ p) {
  __shared__ float sA[FHID][64];         // [k][node], 32 KB
  __shared__ float sW[FHID * 64];        // [k][j], j<32 -> W2, else W3, 32 KB
  const int t = threadIdx.x;
  const int node0 = blockIdx.x * 64;
  for (int f = t; f < FHID * FOUT / 4; f += 256) {
    int k = f >> 3, jq = f & 7;
    *(float4*)&sW[k * 64 + jq * 4]      = *(const float4*)&W2[k * FOUT + jq * 4];
  }
  for (int f = t; f < FHID * FOUT / 4; f += 256) {
    int k = f >> 3, jq = f & 7;
    *(float4*)&sW[k * 64 + 32 + jq * 4] = *(const float4*)&W3[k * FOUT + jq * 4];
  }
  for (int f = t; f < 64 * (FHID / 4); f += 256) {
    int node = f & 63, kq = f >> 6;
    float4 v = *(const float4*)&h[(size_t)(node0 + node) * FHID + kq * 4];
    sA[kq * 4 + 0][node] = v.x;
    sA[kq * 4 + 1][node] = v.y;
    sA[kq * 4 + 2][node] = v.z;
    sA[kq * 4 + 3][node] = v.w;
  }
  __syncthreads();
  const int tx = t & 15, ty = t >> 4;    // j0 = tx*4, n0 = ty*4
  float acc[4][4];
#pragma unroll
  for (int r = 0; r < 4; ++r)
#pragma unroll
    for (int c = 0; c < 4; ++c) acc[r][c] = 0.0f;
#pragma unroll 4
  for (int k = 0; k < FHID; ++k) {
    float4 a = *(float4*)&sA[k][ty * 4];
    float4 w = *(float4*)&sW[k * 64 + tx * 4];
    float av[4] = {a.x, a.y, a.z, a.w};
    float wv[4] = {w.x, w.y, w.z, w.w};
#pragma unroll
    for (int r = 0; r < 4; ++r)
#pragma unroll
      for (int c = 0; c < 4; ++c) acc[r][c] = fmaf(av[r], wv[c], acc[r][c]);
  }
#pragma unroll
  for (int r = 0; r < 4; ++r) {
    float4 o = {acc[r][0], acc[r][1], acc[r][2], acc[r][3]};
    *(float4*)&p[(size_t)(node0 + ty * 4 + r) * 64 + tx * 4] = o;
  }
}

// ------------------------------------------------- adj = sigmoid(z z^T) per graph
// SROA-safe: no address-taken local arrays (the old ar[]/ac[] float4-cast
// pattern demoted them to scratch -> ~4 GB of scratch traffic per call).
// Col tile split into two contiguous float4 groups (tx*4, 64+tx*4) so the
// sC ds_read_b128 hits all 8 bank residues (2-way = free) instead of 4-way.
__global__ __launch_bounds__(256) void k_adj(
    const float* __restrict__ mean_, const float* __restrict__ logstd_,
    const float* __restrict__ noise, float* __restrict__ adj) {
  __shared__ float sR[FOUT][128];
  __shared__ float sC[FOUT][128];
  const int g  = blockIdx.z;
  const int c0 = blockIdx.x * 128;
  const int r0 = blockIdx.y * 128;
  const int t  = threadIdx.x;
  const size_t gb = (size_t)g * NPG;
  for (int f = t; f < 2048; f += 256) {
    int half = f >> 10;
    int ff   = f & 1023;
    int node = ff & 127, kq = ff >> 7;
    int base = half ? c0 : r0;
    size_t idx = (gb + base + node) * FOUT + kq * 4;
    float4 m  = *(const float4*)&mean_[idx];
    float4 l  = *(const float4*)&logstd_[idx];
    float4 nz = *(const float4*)&noise[idx];
    float* s = half ? &sC[0][0] : &sR[0][0];
    s[(kq * 4 + 0) * 128 + node] = m.x + nz.x * __expf(l.x);
    s[(kq * 4 + 1) * 128 + node] = m.y + nz.y * __expf(l.y);
    s[(kq * 4 + 2) * 128 + node] = m.z + nz.z * __expf(l.z);
    s[(kq * 4 + 3) * 128 + node] = m.w + nz.w * __expf(l.w);
  }
  __syncthreads();
  const int tx = t & 15, ty = t >> 4;
  float acc[8][8];
#pragma unroll
  for (int r = 0; r < 8; ++r)
#pragma unroll
    for (int c = 0; c < 8; ++c) acc[r][c] = 0.0f;
#pragma unroll 2
  for (int k = 0; k < FOUT; ++k) {
    float4 a0 = *(const float4*)&sR[k][ty * 8];
    float4 a1 = *(const float4*)&sR[k][ty * 8 + 4];
    float4 q0 = *(const float4*)&sC[k][tx * 4];
    float4 q1 = *(const float4*)&sC[k][tx * 4 + 64];
    float av[8] = {a0.x, a0.y, a0.z, a0.w, a1.x, a1.y, a1.z, a1.w};
    float cv[8] = {q0.x, q0.y, q0.z, q0.w, q1.x, q1.y, q1.z, q1.w};
#pragma unroll
    for (int r = 0; r < 8; ++r)
#pragma unroll
      for (int c = 0; c < 8; ++c) acc[r][c] = fmaf(av[r], cv[c], acc[r][c]);
  }
#pragma unroll
  for (int r = 0; r < 8; ++r) {
    size_t row = gb + r0 + ty * 8 + r;
    float4 s0, s1;
    s0.x = __builtin_amdgcn_rcpf(1.0f + __expf(-acc[r][0]));
    s0.y = __builtin_amdgcn_rcpf(1.0f + __expf(-acc[r][1]));
    s0.z = __builtin_amdgcn_rcpf(1.0f + __expf(-acc[r][2]));
    s0.w = __builtin_amdgcn_rcpf(1.0f + __expf(-acc[r][3]));
    s1.x = __builtin_amdgcn_rcpf(1.0f + __expf(-acc[r][4]));
    s1.y = __builtin_amdgcn_rcpf(1.0f + __expf(-acc[r][5]));
    s1.z = __builtin_amdgcn_rcpf(1.0f + __expf(-acc[r][6]));
    s1.w = __builtin_amdgcn_rcpf(1.0f + __expf(-acc[r][7]));
    *(float4*)&adj[row * NPG + c0 + tx * 4]      = s0;
    *(float4*)&adj[row * NPG + c0 + 64 + tx * 4] = s1;
  }
}

extern "C" void kernel_launch(void* const* d_in, const int* in_sizes, int n_in,
                              void* d_out, int out_size, void* d_ws, size_t ws_size,
                              hipStream_t stream) {
  const float* features = (const float*)d_in[0];
  const int*   src      = (const int*)d_in[1];
  const int*   dst      = (const int*)d_in[2];
  const float* noise    = (const float*)d_in[3];
  const float* W1       = (const float*)d_in[4];
  const float* b1       = (const float*)d_in[5];
  const float* W2       = (const float*)d_in[6];
  const float* b2       = (const float*)d_in[7];
  const float* W3       = (const float*)d_in[8];
  const float* b3       = (const float*)d_in[9];

  float* adj     = (float*)d_out;                              // 64*1024*1024
  float* mean_   = adj + (size_t)NB * NPG * NPG;               // N*32
  float* logstd_ = mean_ + (size_t)NTOT * FOUT;                // N*32

  // Scratch inside the adj region (adj is written only by k_adj, which reads
  // only mean_/logstd_/noise -- all outside this region).
  float* x1   = adj;                              // N*64  (features * rs_out)
  float* m1   = x1 + (size_t)NTOT * FIN;          // N*64  (rs_in-scaled agg)
  float* h    = m1 + (size_t)NTOT * FIN;          // N*128
  float* p    = h + (size_t)NTOT * FHID;          // N*64
  int*   dego = (int*)(p + (size_t)NTOT * FIN);   // N ints
  int*   degi = dego + NTOT;                      // N ints
  float* rso  = (float*)(degi + NTOT);            // N
  float* rsi  = rso + NTOT;                       // N
  int*   ptr  = (int*)(rsi + NTOT);               // N+1
  int*   cur  = ptr + (NTOT + 1);                 // N
  int*   csr  = cur + NTOT;                       // ETOT (4 MB)

  hipMemsetAsync(dego, 0, (size_t)2 * NTOT * sizeof(int), stream);
  k_deg<<<dim3(NB, 4), 1024, 0, stream>>>(src, dst, dego, degi);
  k_scales<<<NTOT / 256, 256, 0, stream>>>(dego, degi, rso, rsi);
  // CSR (built once, used by both layers)
  k_scan<<<NB, 1024, 0, stream>>>(degi, ptr, cur);
  k_fill<<<ETOT / 256, 256, 0, stream>>>(src, dst, cur, csr);
  k_prefold<<<NTOT * 16 / 256, 256, 0, stream>>>(features, dego, x1);
  // layer 1 aggregate: m1 = rs_in * Agg(x1)
  k_agg_csr<<<NTOT / 4, 256, 0, stream>>>(ptr, csr, x1, rsi, m1);
  // h = relu(m1 @ W1 + b1) * rs_out
  k_gemm1<<<NTOT / 64, 256, 0, stream>>>(m1, rso, W1, b1, h);
  // p = h @ [W2 | W3]  (project BEFORE aggregating: halves scatter traffic)
  k_gemm2<<<NTOT / 64, 256, 0, stream>>>(h, W2, W3, p);
  // layer 2 aggregate + bias + split: mean_, logstd_
  k_agg2<<<NTOT / 4, 256, 0, stream>>>(ptr, csr, p, rsi, b2, b3, mean_, logstd_);
  k_adj<<<dim3(NPG / 128, NPG / 128, NB), 256, 0, stream>>>(mean_, logstd_, noise, adj);
}

// Round 4
// 516.619 us; speedup vs baseline: 2.1877x; 1.0234x over previous
//
#include <hip/hip_runtime.h>

constexpr int NB   = 64;                 // graphs per batch
constexpr int NPG  = 1024;               // nodes per graph
constexpr int EPG  = 16384;              // edges per graph
constexpr int NTOT = NB * NPG;           // 65536 nodes
constexpr int ETOT = NB * EPG;           // 1048576 edges
constexpr int FIN  = 64;
constexpr int FHID = 128;
constexpr int FOUT = 32;

// ------------------------------------------------- fused graph preprocessing
// One block per graph (1024 threads == NPG). Histogram both degree arrays in
// LDS, emit rs_out/rs_in, Hillis-Steele scan of in-degree, then fill the CSR
// with LDS cursors. Replaces memset+k_deg+k_scales+k_scan+k_fill (5 -> 1
// dispatch) and removes all global atomics.
__global__ __launch_bounds__(1024) void k_graph(
    const int* __restrict__ src, const int* __restrict__ dst,
    float* __restrict__ rso, float* __restrict__ rsi,
    int* __restrict__ ptr, int* __restrict__ csr) {
  __shared__ int so[NPG], si[NPG], sc[NPG], cur[NPG];
  const int g = blockIdx.x, t = threadIdx.x;
  const int eb = g * EPG, gb = g * NPG;
  so[t] = 0; si[t] = 0;
  __syncthreads();
  for (int e = t; e < EPG; e += 1024) {
    atomicAdd(&so[src[eb + e] - gb], 1);
    atomicAdd(&si[dst[eb + e] - gb], 1);
  }
  __syncthreads();
  const int dgo = so[t];
  const int dgi = si[t];
  rso[gb + t] = rsqrtf((float)(dgo > 1 ? dgo : 1));
  rsi[gb + t] = rsqrtf((float)(dgi > 1 ? dgi : 1));
  // exclusive scan of in-degrees (same verified pattern as old k_scan)
  sc[t] = dgi;
  __syncthreads();
  for (int off = 1; off < NPG; off <<= 1) {
    int v = (t >= off) ? sc[t - off] : 0;
    __syncthreads();
    sc[t] += v;
    __syncthreads();
  }
  const int loc = sc[t] - dgi;              // exclusive, graph-local
  ptr[gb + t] = eb + loc;                   // absolute
  cur[t] = loc;
  if (g == 0 && t == 0) ptr[NTOT] = ETOT;
  __syncthreads();
  for (int e = t; e < EPG; e += 1024) {
    int d = dst[eb + e] - gb;
    int pos = atomicAdd(&cur[d], 1);        // LDS cursor, graph-local
    csr[eb + pos] = src[eb + e];            // absolute src index
  }
}

// ------------------------------------------------- prefold: x1 = features * rs_out
__global__ void k_prefold(const float* __restrict__ features,
                          const float* __restrict__ rso, float* __restrict__ x1) {
  int t = blockIdx.x * blockDim.x + threadIdx.x;   // NTOT*16 threads
  int node = t >> 4, q = t & 15;
  float sc = rso[node];
  float4 v = *(const float4*)&features[(size_t)node * FIN + q * 4];
  v.x *= sc; v.y *= sc; v.z *= sc; v.w *= sc;
  *(float4*)&x1[(size_t)node * FIN + q * 4] = v;
}

// ------------------------------------------------- CSR aggregation (layer 1)
// One wave per destination node; lane = feature dim (64 = FIN).
__global__ __launch_bounds__(256) void k_agg_csr(
    const int* __restrict__ ptr, const int* __restrict__ csr,
    const float* __restrict__ x, const float* __restrict__ rsi,
    float* __restrict__ out) {
  const int nblk = gridDim.x;                       // 16384, divisible by 8
  const int bid  = blockIdx.x;
  const int swz  = (bid & 7) * (nblk >> 3) + (bid >> 3);   // XCD-contiguous
  const int node = swz * 4 + (threadIdx.x >> 6);
  const int lane = threadIdx.x & 63;

  const int start = ptr[node];
  const int end   = ptr[node + 1];
  const int deg   = end - start;

  float acc = 0.0f;
  const float* xb = x + lane;
  if (deg > 0) {
    const int jm = deg < 64 ? deg : 64;
    const int idxv = csr[start + (lane < jm ? lane : 0)];   // 1 coalesced load
    for (int j = 0; j < jm; j += 8) {
      int   sj[8];
      float vj[8];
#pragma unroll
      for (int u = 0; u < 8; ++u) {
        int l = j + u;
        sj[u] = __builtin_amdgcn_readlane(idxv, l < jm ? l : 0);
      }
#pragma unroll
      for (int u = 0; u < 8; ++u) vj[u] = xb[(size_t)sj[u] * FIN];
#pragma unroll
      for (int u = 0; u < 8; ++u) acc += (j + u < jm) ? vj[u] : 0.0f;
    }
    for (int e = start + 64; e < end; ++e) acc += xb[(size_t)csr[e] * FIN];
  }
  out[(size_t)node * FIN + lane] = acc * rsi[node];
}

// ------------------------------------------------- CSR aggregation (layer 2)
// Same gather; epilogue fuses rs_in scale + bias and splits mean/logstd.
__global__ __launch_bounds__(256) void k_agg2(
    const int* __restrict__ ptr, const int* __restrict__ csr,
    const float* __restrict__ x, const float* __restrict__ rsi,
    const float* __restrict__ b2, const float* __restrict__ b3,
    float* __restrict__ mean_, float* __restrict__ logstd_) {
  const int nblk = gridDim.x;
  const int bid  = blockIdx.x;
  const int swz  = (bid & 7) * (nblk >> 3) + (bid >> 3);
  const int node = swz * 4 + (threadIdx.x >> 6);
  const int lane = threadIdx.x & 63;

  const int start = ptr[node];
  const int end   = ptr[node + 1];
  const int deg   = end - start;

  float acc = 0.0f;
  const float* xb = x + lane;
  if (deg > 0) {
    const int jm = deg < 64 ? deg : 64;
    const int idxv = csr[start + (lane < jm ? lane : 0)];
    for (int j = 0; j < jm; j += 8) {
      int   sj[8];
      float vj[8];
#pragma unroll
      for (int u = 0; u < 8; ++u) {
        int l = j + u;
        sj[u] = __builtin_amdgcn_readlane(idxv, l < jm ? l : 0);
      }
#pragma unroll
      for (int u = 0; u < 8; ++u) vj[u] = xb[(size_t)sj[u] * FIN];
#pragma unroll
      for (int u = 0; u < 8; ++u) acc += (j + u < jm) ? vj[u] : 0.0f;
    }
    for (int e = start + 64; e < end; ++e) acc += xb[(size_t)csr[e] * FIN];
  }
  const float bias = (lane < FOUT) ? b2[lane] : b3[lane - FOUT];
  const float v = acc * rsi[node] + bias;
  if (lane < FOUT) mean_[(size_t)node * FOUT + lane] = v;
  else             logstd_[(size_t)node * FOUT + (lane - FOUT)] = v;
}

// ------------------------------------------------- fused GEMM1+GEMM2
// h = relu(m1@W1 + b1) * rs_out stays in LDS (sH); p = h @ [W2 | W3].
// Removes the 32 MB h round-trip and one dispatch. 112.5 KB LDS -> 1 block/CU.
__global__ __launch_bounds__(256) void k_gemm12(
    const float* __restrict__ m1, const float* __restrict__ rso,
    const float* __restrict__ W1, const float* __restrict__ b1,
    const float* __restrict__ W2, const float* __restrict__ W3,
    float* __restrict__ p) {
  __shared__ float sA[FIN][64];          // 16 KB  [k][node]
  __shared__ float sW1[FIN * FHID];      // 32 KB  [k][j]
  __shared__ float sB[FHID];
  __shared__ float sH[FHID][64];         // 32 KB  [k][node]
  __shared__ float sW23[FHID * 64];      // 32 KB  [k][j], j<32 W2 else W3
  const int t = threadIdx.x;
  const int node0 = blockIdx.x * 64;
  // stage W1, b1, A, W2|W3
  for (int f = t; f < FIN * FHID / 4; f += 256)
    ((float4*)sW1)[f] = ((const float4*)W1)[f];
  if (t < FHID) sB[t] = b1[t];
  for (int f = t; f < 64 * (FIN / 4); f += 256) {
    int node = f & 63, kq = f >> 6;
    size_t idx = (size_t)(node0 + node) * FIN + kq * 4;
    float4 va = *(const float4*)&m1[idx];
    sA[kq * 4 + 0][node] = va.x;
    sA[kq * 4 + 1][node] = va.y;
    sA[kq * 4 + 2][node] = va.z;
    sA[kq * 4 + 3][node] = va.w;
  }
  for (int f = t; f < FHID * FOUT / 4; f += 256) {
    int k = f >> 3, jq = f & 7;
    *(float4*)&sW23[k * 64 + jq * 4]      = *(const float4*)&W2[k * FOUT + jq * 4];
  }
  for (int f = t; f < FHID * FOUT / 4; f += 256) {
    int k = f >> 3, jq = f & 7;
    *(float4*)&sW23[k * 64 + 32 + jq * 4] = *(const float4*)&W3[k * FOUT + jq * 4];
  }
  __syncthreads();
  const int tx = t & 15, ty = t >> 4;    // gemm1: j0 = tx*8, n0 = ty*4
  {
    float acc[4][8];
#pragma unroll
    for (int r = 0; r < 4; ++r)
#pragma unroll
      for (int c = 0; c < 8; ++c) acc[r][c] = 0.0f;
#pragma unroll 4
    for (int k = 0; k < FIN; ++k) {
      float4 a  = *(float4*)&sA[k][ty * 4];
      float4 w0 = *(float4*)&sW1[k * FHID + tx * 8];
      float4 w1 = *(float4*)&sW1[k * FHID + tx * 8 + 4];
      float av[4] = {a.x, a.y, a.z, a.w};
      float wv[8] = {w0.x, w0.y, w0.z, w0.w, w1.x, w1.y, w1.z, w1.w};
#pragma unroll
      for (int r = 0; r < 4; ++r)
#pragma unroll
        for (int c = 0; c < 8; ++c) acc[r][c] = fmaf(av[r], wv[c], acc[r][c]);
    }
    float s0 = rso[node0 + ty * 4 + 0];
    float s1 = rso[node0 + ty * 4 + 1];
    float s2 = rso[node0 + ty * 4 + 2];
    float s3 = rso[node0 + ty * 4 + 3];
#pragma unroll
    for (int c = 0; c < 8; ++c) {
      float b = sB[tx * 8 + c];
      float4 v;
      v.x = fmaxf(acc[0][c] + b, 0.f) * s0;
      v.y = fmaxf(acc[1][c] + b, 0.f) * s1;
      v.z = fmaxf(acc[2][c] + b, 0.f) * s2;
      v.w = fmaxf(acc[3][c] + b, 0.f) * s3;
      *(float4*)&sH[tx * 8 + c][ty * 4] = v;   // one-time write, outside k-loop
    }
  }
  __syncthreads();
  {                                       // gemm2: j0 = tx*4, n0 = ty*4
    float acc[4][4];
#pragma unroll
    for (int r = 0; r < 4; ++r)
#pragma unroll
      for (int c = 0; c < 4; ++c) acc[r][c] = 0.0f;
#pragma unroll 4
    for (int k = 0; k < FHID; ++k) {
      float4 a = *(float4*)&sH[k][ty * 4];
      float4 w = *(float4*)&sW23[k * 64 + tx * 4];
      float av[4] = {a.x, a.y, a.z, a.w};
      float wv[4] = {w.x, w.y, w.z, w.w};
#pragma unroll
      for (int r = 0; r < 4; ++r)
#pragma unroll
        for (int c = 0; c < 4; ++c) acc[r][c] = fmaf(av[r], wv[c], acc[r][c]);
    }
#pragma unroll
    for (int r = 0; r < 4; ++r) {
      float4 o = {acc[r][0], acc[r][1], acc[r][2], acc[r][3]};
      *(float4*)&p[(size_t)(node0 + ty * 4 + r) * 64 + tx * 4] = o;
    }
  }
}

// ------------------------------------------------- adj = sigmoid(z z^T) per graph
__global__ __launch_bounds__(256) void k_adj(
    const float* __restrict__ mean_, const float* __restrict__ logstd_,
    const float* __restrict__ noise, float* __restrict__ adj) {
  __shared__ float sR[FOUT][128];
  __shared__ float sC[FOUT][128];
  const int g  = blockIdx.z;
  const int c0 = blockIdx.x * 128;
  const int r0 = blockIdx.y * 128;
  const int t  = threadIdx.x;
  const size_t gb = (size_t)g * NPG;
  for (int f = t; f < 2048; f += 256) {
    int half = f >> 10;
    int ff   = f & 1023;
    int node = ff & 127, kq = ff >> 7;
    int base = half ? c0 : r0;
    size_t idx = (gb + base + node) * FOUT + kq * 4;
    float4 m  = *(const float4*)&mean_[idx];
    float4 l  = *(const float4*)&logstd_[idx];
    float4 nz = *(const float4*)&noise[idx];
    float* s = half ? &sC[0][0] : &sR[0][0];
    s[(kq * 4 + 0) * 128 + node] = m.x + nz.x * __expf(l.x);
    s[(kq * 4 + 1) * 128 + node] = m.y + nz.y * __expf(l.y);
    s[(kq * 4 + 2) * 128 + node] = m.z + nz.z * __expf(l.z);
    s[(kq * 4 + 3) * 128 + node] = m.w + nz.w * __expf(l.w);
  }
  __syncthreads();
  const int tx = t & 15, ty = t >> 4;
  float acc[8][8];
#pragma unroll
  for (int r = 0; r < 8; ++r)
#pragma unroll
    for (int c = 0; c < 8; ++c) acc[r][c] = 0.0f;
#pragma unroll 2
  for (int k = 0; k < FOUT; ++k) {
    float4 a0 = *(const float4*)&sR[k][ty * 8];
    float4 a1 = *(const float4*)&sR[k][ty * 8 + 4];
    float4 q0 = *(const float4*)&sC[k][tx * 4];
    float4 q1 = *(const float4*)&sC[k][tx * 4 + 64];
    float av[8] = {a0.x, a0.y, a0.z, a0.w, a1.x, a1.y, a1.z, a1.w};
    float cv[8] = {q0.x, q0.y, q0.z, q0.w, q1.x, q1.y, q1.z, q1.w};
#pragma unroll
    for (int r = 0; r < 8; ++r)
#pragma unroll
      for (int c = 0; c < 8; ++c) acc[r][c] = fmaf(av[r], cv[c], acc[r][c]);
  }
#pragma unroll
  for (int r = 0; r < 8; ++r) {
    size_t row = gb + r0 + ty * 8 + r;
    float4 s0, s1;
    s0.x = __builtin_amdgcn_rcpf(1.0f + __expf(-acc[r][0]));
    s0.y = __builtin_amdgcn_rcpf(1.0f + __expf(-acc[r][1]));
    s0.z = __builtin_amdgcn_rcpf(1.0f + __expf(-acc[r][2]));
    s0.w = __builtin_amdgcn_rcpf(1.0f + __expf(-acc[r][3]));
    s1.x = __builtin_amdgcn_rcpf(1.0f + __expf(-acc[r][4]));
    s1.y = __builtin_amdgcn_rcpf(1.0f + __expf(-acc[r][5]));
    s1.z = __builtin_amdgcn_rcpf(1.0f + __expf(-acc[r][6]));
    s1.w = __builtin_amdgcn_rcpf(1.0f + __expf(-acc[r][7]));
    *(float4*)&adj[row * NPG + c0 + tx * 4]      = s0;
    *(float4*)&adj[row * NPG + c0 + 64 + tx * 4] = s1;
  }
}

extern "C" void kernel_launch(void* const* d_in, const int* in_sizes, int n_in,
                              void* d_out, int out_size, void* d_ws, size_t ws_size,
                              hipStream_t stream) {
  const float* features = (const float*)d_in[0];
  const int*   src      = (const int*)d_in[1];
  const int*   dst      = (const int*)d_in[2];
  const float* noise    = (const float*)d_in[3];
  const float* W1       = (const float*)d_in[4];
  const float* b1       = (const float*)d_in[5];
  const float* W2       = (const float*)d_in[6];
  const float* b2       = (const float*)d_in[7];
  const float* W3       = (const float*)d_in[8];
  const float* b3       = (const float*)d_in[9];

  float* adj     = (float*)d_out;                              // 64*1024*1024
  float* mean_   = adj + (size_t)NB * NPG * NPG;               // N*32
  float* logstd_ = mean_ + (size_t)NTOT * FOUT;                // N*32

  // Scratch inside the adj region (adj is written only by k_adj, which reads
  // only mean_/logstd_/noise -- all outside this region).
  float* x1   = adj;                              // N*64  (features * rs_out)
  float* m1   = x1 + (size_t)NTOT * FIN;          // N*64  (rs_in-scaled agg)
  float* p    = m1 + (size_t)NTOT * FIN;          // N*64
  float* rso  = p + (size_t)NTOT * FIN;           // N
  float* rsi  = rso + NTOT;                       // N
  int*   ptr  = (int*)(rsi + NTOT);               // N+1
  int*   csr  = ptr + (NTOT + 1);                 // ETOT (4 MB)

  // fused preprocessing: degrees + scales + scan + CSR fill
  k_graph<<<NB, 1024, 0, stream>>>(src, dst, rso, rsi, ptr, csr);
  k_prefold<<<NTOT * 16 / 256, 256, 0, stream>>>(features, rso, x1);
  // layer 1 aggregate: m1 = rs_in * Agg(x1)
  k_agg_csr<<<NTOT / 4, 256, 0, stream>>>(ptr, csr, x1, rsi, m1);
  // fused: h = relu(m1@W1+b1)*rs_out (LDS-resident), p = h @ [W2 | W3]
  k_gemm12<<<NTOT / 64, 256, 0, stream>>>(m1, rso, W1, b1, W2, W3, p);
  // layer 2 aggregate + bias + split: mean_, logstd_
  k_agg2<<<NTOT / 4, 256, 0, stream>>>(ptr, csr, p, rsi, b2, b3, mean_, logstd_);
  k_adj<<<dim3(NPG / 128, NPG / 128, NB), 256, 0, stream>>>(mean_, logstd_, noise, adj);
}